// Round 8
// baseline (920.707 us; speedup 1.0000x reference)
//
#include <hip/hip_runtime.h>
#include <hip/hip_bf16.h>
#include <math.h>

typedef __attribute__((ext_vector_type(8))) __bf16 bf16x8;
typedef __attribute__((ext_vector_type(4))) float floatx4;

__device__ inline unsigned short f2u(float f) {
  __hip_bfloat16 h = __float2bfloat16(f);
  unsigned short u;
  __builtin_memcpy(&u, &h, 2);
  return u;
}

__device__ inline floatx4 mfma16(bf16x8 a, bf16x8 b, floatx4 c) {
  return __builtin_amdgcn_mfma_f32_16x16x32_bf16(a, b, c, 0, 0, 0);
}

__device__ inline void gload_lds16(const unsigned short* g, unsigned short* l) {
  __builtin_amdgcn_global_load_lds(
      (__attribute__((address_space(1))) void*)g,
      (__attribute__((address_space(3))) void*)l,
      16, 0, 0);
}

// ---------------- cast fp32 -> bf16 (vectorized, optional scale) ----------------
__global__ __launch_bounds__(256) void castk(const float* __restrict__ in,
                                             unsigned short* __restrict__ out,
                                             int n4, float scale) {
  int i = blockIdx.x * 256 + threadIdx.x;
  if (i >= n4) return;
  const float4 v = reinterpret_cast<const float4*>(in)[i];
  ushort4 o;
  o.x = f2u(v.x * scale);
  o.y = f2u(v.y * scale);
  o.z = f2u(v.z * scale);
  o.w = f2u(v.w * scale);
  reinterpret_cast<ushort4*>(out)[i] = o;
}

// fused cast of the 4 weight matrices (each 1,048,576 float4), wq scaled
__global__ __launch_bounds__(256) void castw4(const float* __restrict__ wq,
                                              const float* __restrict__ wk,
                                              const float* __restrict__ wv,
                                              const float* __restrict__ wo,
                                              unsigned short* __restrict__ oq,
                                              unsigned short* __restrict__ ok,
                                              unsigned short* __restrict__ ov,
                                              unsigned short* __restrict__ oo,
                                              float qscale) {
  const int tensor = blockIdx.x >> 12;
  const int i = (blockIdx.x & 4095) * 256 + threadIdx.x;
  const float* in = tensor == 0 ? wq : tensor == 1 ? wk : tensor == 2 ? wv : wo;
  unsigned short* out = tensor == 0 ? oq : tensor == 1 ? ok : tensor == 2 ? ov : oo;
  const float s = tensor == 0 ? qscale : 1.0f;
  const float4 v = reinterpret_cast<const float4*>(in)[i];
  ushort4 o;
  o.x = f2u(v.x * s);
  o.y = f2u(v.y * s);
  o.z = f2u(v.z * s);
  o.w = f2u(v.w * s);
  reinterpret_cast<ushort4*>(out)[i] = o;
}

// ---------------- 256x256 8-phase GEMM (unchanged from R6/R7) ----------
template <int OUT>
__global__ __launch_bounds__(512, 2)
void gemm256(const unsigned short* __restrict__ A,
             const unsigned short* __restrict__ B,
             unsigned short* __restrict__ Cb,
             float* __restrict__ Cf,
             const float* __restrict__ bias,
             int M, int N, int K) {
  extern __shared__ unsigned short lds[];
  const int t = threadIdx.x;
  const int w = t >> 6;
  const int l = t & 63;
  const int wm = w >> 2;
  const int wn = w & 3;
  const int fr = l & 15;
  const int fkb = l >> 4;
  const int key = fr & 7;
  const int sslot = (l & 7) ^ (l >> 3);

  const int m0 = blockIdx.y * 256;
  const int n0 = blockIdx.x * 256;
  const int T = K >> 6;

  auto stage = [&](const unsigned short* G, int rb, int kt2, int h, int ldsbase) {
    const int d2 = kt2 & 1;
    const int rt = h * 128 + w * 16 + (l >> 3);
    const unsigned short* s0 = G + (size_t)(rb + rt) * K + kt2 * 64 + sslot * 8;
    unsigned short* dst = lds + ldsbase + d2 * 16384 + h * 8192 + w * 1024;
    gload_lds16(s0, dst);
    gload_lds16(s0 + (size_t)8 * K, dst + 512);
  };

  floatx4 acc[8][4];
#pragma unroll
  for (int m = 0; m < 8; m++)
#pragma unroll
    for (int n = 0; n < 4; n++) acc[m][n] = (floatx4){0.f, 0.f, 0.f, 0.f};

  stage(A, m0, 0, 0, 0);
  stage(A, m0, 0, 1, 0);
  stage(B, n0, 0, 0, 32768);
  stage(B, n0, 0, 1, 32768);
  if (1 < T) {
    stage(B, n0, 1, 0, 32768);
    stage(B, n0, 1, 1, 32768);
    asm volatile("s_waitcnt vmcnt(4)" ::: "memory");
  } else {
    asm volatile("s_waitcnt vmcnt(0)" ::: "memory");
  }
  __builtin_amdgcn_s_barrier();

#define GPHASE(q, STAGE_STMT)                                               \
  {                                                                         \
    bf16x8 a00 = *reinterpret_cast<const bf16x8*>(                          \
        Ab + (wm * 128 + (2 * (q)) * 16 + fr) * 64 + ((fkb ^ key)) * 8);    \
    bf16x8 a01 = *reinterpret_cast<const bf16x8*>(                          \
        Ab + (wm * 128 + (2 * (q)) * 16 + fr) * 64 + (((4 + fkb) ^ key)) * 8); \
    bf16x8 a10 = *reinterpret_cast<const bf16x8*>(                          \
        Ab + (wm * 128 + (2 * (q) + 1) * 16 + fr) * 64 + ((fkb ^ key)) * 8);\
    bf16x8 a11 = *reinterpret_cast<const bf16x8*>(                          \
        Ab + (wm * 128 + (2 * (q) + 1) * 16 + fr) * 64 + (((4 + fkb) ^ key)) * 8); \
    STAGE_STMT;                                                             \
    __builtin_amdgcn_s_barrier();                                           \
    asm volatile("s_waitcnt lgkmcnt(0)");                                   \
    __builtin_amdgcn_s_setprio(1);                                          \
    _Pragma("unroll")                                                       \
    for (int n = 0; n < 4; n++) {                                           \
      acc[2 * (q)][n] = mfma16(a00, bfr[0][n], acc[2 * (q)][n]);            \
      acc[2 * (q)][n] = mfma16(a01, bfr[1][n], acc[2 * (q)][n]);            \
      acc[2 * (q) + 1][n] = mfma16(a10, bfr[0][n], acc[2 * (q) + 1][n]);    \
      acc[2 * (q) + 1][n] = mfma16(a11, bfr[1][n], acc[2 * (q) + 1][n]);    \
    }                                                                       \
    __builtin_amdgcn_s_setprio(0);                                          \
    __builtin_amdgcn_s_barrier();                                           \
  }

  for (int kt = 0; kt < T; ++kt) {
    const int d = kt & 1;
    const unsigned short* Ab = lds + d * 16384;
    const unsigned short* Bb = lds + 32768 + d * 16384;

    bf16x8 bfr[2][4];
#pragma unroll
    for (int kk = 0; kk < 2; kk++)
#pragma unroll
      for (int n = 0; n < 4; n++)
        bfr[kk][n] = *reinterpret_cast<const bf16x8*>(
            Bb + (wn * 64 + n * 16 + fr) * 64 + (((kk * 4 + fkb) ^ key)) * 8);

    GPHASE(0, if (kt + 1 < T) stage(A, m0, kt + 1, 0, 0));
    GPHASE(1, if (kt + 1 < T) stage(A, m0, kt + 1, 1, 0));
    GPHASE(2, if (kt + 2 < T) stage(B, n0, kt + 2, 0, 32768));
    GPHASE(3, {
      if (kt + 2 < T) {
        stage(B, n0, kt + 2, 1, 32768);
        asm volatile("s_waitcnt vmcnt(4)" ::: "memory");
      } else {
        asm volatile("s_waitcnt vmcnt(0)" ::: "memory");
      }
    });
  }
#undef GPHASE

  const int er = (l >> 4) * 4;
  const int ec = l & 15;
#pragma unroll
  for (int m = 0; m < 8; m++) {
#pragma unroll
    for (int n = 0; n < 4; n++) {
      const int col = n0 + wn * 64 + n * 16 + ec;
      if (OUT == 2) {
        const int hv = col >> 7, dh = col & 127;
        const int row0 = m0 + wm * 128 + m * 16 + er;
        const int bb = row0 >> 11;
        const int t0 = row0 & 2047;
        unsigned short* vp =
            Cb + (((size_t)(bb * 16 + hv)) * 128 + dh) * 2048 + t0;
#pragma unroll
        for (int r = 0; r < 4; r++) vp[r] = f2u(acc[m][n][r]);
      } else {
#pragma unroll
        for (int r = 0; r < 4; r++) {
          const int row = m0 + wm * 128 + m * 16 + er + r;
          if (OUT == 1) {
            Cf[(size_t)row * N + col] = acc[m][n][r] + bias[col];
          } else {
            Cb[(size_t)row * N + col] = f2u(acc[m][n][r]);
          }
        }
      }
    }
  }
}

// ---------------- flash attention: 8 waves x 32 q-rows = 256 q-rows/block ----
// Y2: (8192 x 4096) bf16, cols [0,2048)=Q (pre-scaled by log2e/sqrt(Dh)),
// [2048,4096)=K.  Vtg: [64 bh][128 dh][2048 t] bf16.
// Scores are in log2 domain -> exp2f. Softmax common path is shuffle-free:
// per-lane partial-max check + one wave-wide __any vote; lsum kept as
// per-lane partials, reduced once in epilogue. KV tile = 64, K/V single-
// buffered (dynamic LDS 68KB -> 2 blocks/CU = 16 waves/CU).
__global__ __launch_bounds__(512, 4)
void attn_kernel(const unsigned short* __restrict__ Y2,
                 const unsigned short* __restrict__ Vtg,
                 unsigned short* __restrict__ att) {
  extern __shared__ unsigned short smem[];
  // smem: [0,8192) Kt [kvrow 64][slot16 swz], [8192,16384) Vt [dh 128][slot8 swz],
  //       [16384,+8*2304) Pl per-wave [32][72]
  unsigned short* Kt = smem;
  unsigned short* Vt = smem + 8192;
  unsigned short* Pw = smem + 16384 + (threadIdx.x >> 6) * 2304;

  const int t = threadIdx.x;
  const int w = t >> 6;
  const int l = t & 63;
  const int bid = blockIdx.x;
  const int bh = bid & 63;  // bh-fastest (R3-verified HBM behavior)
  const int qt = bid >> 6;  // 0..7, 256 q-rows each
  const int b = bh >> 4;
  const int h = bh & 15;

  const size_t ybase = (size_t)b * 2048 * 4096 + (size_t)h * 128;
  const unsigned short* Qp = Y2 + ybase;
  const unsigned short* Kp = Y2 + ybase + 2048;
  const unsigned short* Vp = Vtg + (size_t)bh * 128 * 2048;

  const int fr = l & 15;
  const int fkb = l >> 4;
  const int key = fr & 7;

  // K staging (512 lanes, 2 calls): call c covers rows c*32+(t>>4), slot t&15.
  const int ksr = t >> 4;
  const int ksl = (t & 15) ^ (ksr & 7);
  const unsigned short* Ksrc = Kp + (size_t)ksr * 4096 + ksl * 8;
  // V staging: call c covers rows c*64+(t>>3), slot t&7.
  const int vsr = t >> 3;
  const int vsl = (t & 7) ^ (vsr & 7);
  const unsigned short* Vsrc = Vp + (size_t)vsr * 2048 + vsl * 8;

  bf16x8 qf[2][4];
#pragma unroll
  for (int i = 0; i < 2; i++)
#pragma unroll
    for (int kk = 0; kk < 4; kk++)
      qf[i][kk] = *reinterpret_cast<const bf16x8*>(
          &Qp[(size_t)(qt * 256 + w * 32 + i * 16 + fr) * 4096 + kk * 32 + fkb * 8]);

  floatx4 oacc[2][8];
#pragma unroll
  for (int i = 0; i < 2; i++)
#pragma unroll
    for (int nt = 0; nt < 8; nt++) oacc[i][nt] = (floatx4){0.f, 0.f, 0.f, 0.f};
  float mrun[2][4], lsum[2][4];
#pragma unroll
  for (int i = 0; i < 2; i++)
#pragma unroll
    for (int r = 0; r < 4; r++) {
      mrun[i][r] = -INFINITY;
      lsum[i][r] = 0.f;
    }

  // prologue: stage K(0), V(0)
#pragma unroll
  for (int c = 0; c < 2; c++)
    gload_lds16(Ksrc + (size_t)c * 32 * 4096, &Kt[c * 4096 + w * 512]);
#pragma unroll
  for (int c = 0; c < 2; c++)
    gload_lds16(Vsrc + (size_t)c * 64 * 2048, &Vt[c * 4096 + w * 512]);
  __syncthreads();  // drains vmcnt: K(0), V(0) ready

  for (int kv = 0; kv < 2048; kv += 64) {
    // ---- QK^T: 32 q-rows x 64 kv from Kt (log2-scaled scores) ----
    floatx4 sacc[2][4];
#pragma unroll
    for (int i = 0; i < 2; i++)
#pragma unroll
      for (int nt = 0; nt < 4; nt++) sacc[i][nt] = (floatx4){0.f, 0.f, 0.f, 0.f};
#pragma unroll
    for (int nt = 0; nt < 4; nt++) {
#pragma unroll
      for (int kk = 0; kk < 4; kk++) {
        bf16x8 kf = *reinterpret_cast<const bf16x8*>(
            &Kt[((nt * 16 + fr) * 16 + ((kk * 4 + fkb) ^ key)) * 8]);
        sacc[0][nt] = mfma16(qf[0][kk], kf, sacc[0][nt]);
        sacc[1][nt] = mfma16(qf[1][kk], kf, sacc[1][nt]);
      }
    }

    // ---- softmax, shuffle-free common path (defer-max THR=11.5 log2) ----
    float mx4[2][4];
    float dmax = -INFINITY;
#pragma unroll
    for (int i = 0; i < 2; i++)
#pragma unroll
      for (int r = 0; r < 4; r++) {
        mx4[i][r] = fmaxf(fmaxf(sacc[i][0][r], sacc[i][1][r]),
                          fmaxf(sacc[i][2][r], sacc[i][3][r]));
        dmax = fmaxf(dmax, mx4[i][r] - mrun[i][r]);
      }
    if (__any(dmax > 11.5f)) {  // rare: full reduce + rescale
#pragma unroll
      for (int i = 0; i < 2; i++)
#pragma unroll
        for (int r = 0; r < 4; r++) {
          float mx = mx4[i][r];
          mx = fmaxf(mx, __shfl_xor(mx, 1));
          mx = fmaxf(mx, __shfl_xor(mx, 2));
          mx = fmaxf(mx, __shfl_xor(mx, 4));
          mx = fmaxf(mx, __shfl_xor(mx, 8));
          const float mn = fmaxf(mrun[i][r], mx);
          const float alpha = exp2f(mrun[i][r] - mn);
          mrun[i][r] = mn;
          lsum[i][r] *= alpha;
#pragma unroll
          for (int nt = 0; nt < 8; nt++) oacc[i][nt][r] *= alpha;
        }
    }
#pragma unroll
    for (int i = 0; i < 2; i++)
#pragma unroll
      for (int r = 0; r < 4; r++) {
        const float m = mrun[i][r];
        const float p0 = exp2f(sacc[i][0][r] - m);
        const float p1 = exp2f(sacc[i][1][r] - m);
        const float p2 = exp2f(sacc[i][2][r] - m);
        const float p3 = exp2f(sacc[i][3][r] - m);
        lsum[i][r] += (p0 + p1) + (p2 + p3);
        const int pr = i * 16 + fkb * 4 + r;
        Pw[pr * 72 + fr] = f2u(p0);
        Pw[pr * 72 + 16 + fr] = f2u(p1);
        Pw[pr * 72 + 32 + fr] = f2u(p2);
        Pw[pr * 72 + 48 + fr] = f2u(p3);
      }

    __syncthreads();  // bar1: Kt reads done; prior V-stage drained

    // ---- stage K(kv+64); latency hides under PV ----
    if (kv + 64 < 2048) {
#pragma unroll
      for (int c = 0; c < 2; c++)
        gload_lds16(Ksrc + (size_t)(kv + 64 + c * 32) * 4096,
                    &Kt[c * 4096 + w * 512]);
    }

    // ---- PV: out(32x128) += P(32x64) @ V(64x128) ----
    bf16x8 pf[2][2];
#pragma unroll
    for (int i = 0; i < 2; i++) {
      pf[i][0] = *reinterpret_cast<const bf16x8*>(&Pw[(i * 16 + fr) * 72 + fkb * 8]);
      pf[i][1] = *reinterpret_cast<const bf16x8*>(&Pw[(i * 16 + fr) * 72 + 32 + fkb * 8]);
    }
#pragma unroll
    for (int nt = 0; nt < 8; nt++) {
      const unsigned short* vr = &Vt[(nt * 16 + fr) * 64];
      bf16x8 vf0 = *reinterpret_cast<const bf16x8*>(vr + (fkb ^ key) * 8);
      bf16x8 vf1 = *reinterpret_cast<const bf16x8*>(vr + ((fkb + 4) ^ key) * 8);
#pragma unroll
      for (int i = 0; i < 2; i++) {
        oacc[i][nt] = mfma16(pf[i][0], vf0, oacc[i][nt]);
        oacc[i][nt] = mfma16(pf[i][1], vf1, oacc[i][nt]);
      }
    }

    __syncthreads();  // bar2: Vt reads done; K(kv+64) drained

    // ---- stage V(kv+64); latency hides under next QK^T+softmax ----
    if (kv + 64 < 2048) {
#pragma unroll
      for (int c = 0; c < 2; c++)
        gload_lds16(Vsrc + (size_t)c * 64 * 2048 + (kv + 64),
                    &Vt[c * 4096 + w * 512]);
    }
  }

  // ---- epilogue: reduce per-lane lsum partials (once), then write ----
#pragma unroll
  for (int i = 0; i < 2; i++) {
#pragma unroll
    for (int r = 0; r < 4; r++) {
      float s = lsum[i][r];
      s += __shfl_xor(s, 1);
      s += __shfl_xor(s, 2);
      s += __shfl_xor(s, 4);
      s += __shfl_xor(s, 8);
      const float inv = 1.0f / s;
      const int row = qt * 256 + w * 32 + i * 16 + fkb * 4 + r;
      unsigned short* op = att + ((size_t)b * 2048 + row) * 2048 + h * 128 + fr;
#pragma unroll
      for (int nt = 0; nt < 8; nt++) op[nt * 16] = f2u(oacc[i][nt][r] * inv);
    }
  }
}

// ---------------- launch ----------------
extern "C" void kernel_launch(void* const* d_in, const int* in_sizes, int n_in,
                              void* d_out, int out_size, void* d_ws, size_t ws_size,
                              hipStream_t stream) {
  const float* x = (const float*)d_in[0];
  const float* wq = (const float*)d_in[1];
  const float* wk = (const float*)d_in[2];
  const float* wv = (const float*)d_in[3];
  const float* wo = (const float*)d_in[4];
  const float* bo = (const float*)d_in[5];

  unsigned short* ws = (unsigned short*)d_ws;
  unsigned short* x16 = ws;                      // 16,777,216
  unsigned short* wqkv16 = x16 + 16777216;       // 12,582,912
  unsigned short* wo16 = wqkv16 + 12582912;      // 4,194,304
  unsigned short* Y2 = wo16 + 4194304;           // 33,554,432 (8192 x 4096, Q|K)
  unsigned short* Vtg = Y2 + 33554432;           // 16,777,216 (64 x 128 x 2048)
  unsigned short* att16 = Vtg + 16777216;        // 16,777,216
  // total 100,663,296 ushorts = 201.3 MB

  // log2(e)/sqrt(128): scores land in log2 domain -> exp2f softmax
  const float sscale = 0.12751744900765256f;

  hipFuncSetAttribute(reinterpret_cast<const void*>(gemm256<0>),
                      hipFuncAttributeMaxDynamicSharedMemorySize, 131072);
  hipFuncSetAttribute(reinterpret_cast<const void*>(gemm256<1>),
                      hipFuncAttributeMaxDynamicSharedMemorySize, 131072);
  hipFuncSetAttribute(reinterpret_cast<const void*>(gemm256<2>),
                      hipFuncAttributeMaxDynamicSharedMemorySize, 131072);
  hipFuncSetAttribute(reinterpret_cast<const void*>(attn_kernel),
                      hipFuncAttributeMaxDynamicSharedMemorySize, 69632);

  castk<<<16384, 256, 0, stream>>>(x, x16, 4194304, 1.0f);
  castw4<<<16384, 256, 0, stream>>>(wq, wk, wv, wo,
                                    wqkv16, wqkv16 + 4194304,
                                    wqkv16 + 8388608, wo16, sscale);

  // Q,K projections -> Y2 (row-major)
  dim3 gqk(16, 32);
  gemm256<0><<<gqk, 512, 131072, stream>>>(x16, wqkv16, Y2, nullptr, nullptr,
                                           8192, 4096, 2048);
  // V projection -> Vtg (transposed per head)
  dim3 gv(8, 32);
  gemm256<2><<<gv, 512, 131072, stream>>>(x16, wqkv16 + 8388608, Vtg, nullptr,
                                          nullptr, 8192, 2048, 2048);

  attn_kernel<<<512, 512, 69632, stream>>>(Y2, Vtg, att16);

  dim3 go(8, 32);
  gemm256<1><<<go, 512, 131072, stream>>>(att16, wo16, nullptr, (float*)d_out,
                                          bo, 8192, 2048, 2048);
}

// Round 9
// 483.496 us; speedup vs baseline: 1.9043x; 1.9043x over previous
//
#include <hip/hip_runtime.h>
#include <hip/hip_bf16.h>
#include <math.h>

typedef __attribute__((ext_vector_type(8))) __bf16 bf16x8;
typedef __attribute__((ext_vector_type(4))) float floatx4;

__device__ inline unsigned short f2u(float f) {
  __hip_bfloat16 h = __float2bfloat16(f);
  unsigned short u;
  __builtin_memcpy(&u, &h, 2);
  return u;
}

__device__ inline floatx4 mfma16(bf16x8 a, bf16x8 b, floatx4 c) {
  return __builtin_amdgcn_mfma_f32_16x16x32_bf16(a, b, c, 0, 0, 0);
}

__device__ inline void gload_lds16(const unsigned short* g, unsigned short* l) {
  __builtin_amdgcn_global_load_lds(
      (__attribute__((address_space(1))) void*)g,
      (__attribute__((address_space(3))) void*)l,
      16, 0, 0);
}

// ---------------- cast fp32 -> bf16 (vectorized, optional scale) ----------------
__global__ __launch_bounds__(256) void castk(const float* __restrict__ in,
                                             unsigned short* __restrict__ out,
                                             int n4, float scale) {
  int i = blockIdx.x * 256 + threadIdx.x;
  if (i >= n4) return;
  const float4 v = reinterpret_cast<const float4*>(in)[i];
  ushort4 o;
  o.x = f2u(v.x * scale);
  o.y = f2u(v.y * scale);
  o.z = f2u(v.z * scale);
  o.w = f2u(v.w * scale);
  reinterpret_cast<ushort4*>(out)[i] = o;
}

// fused cast of the 4 weight matrices (each 1,048,576 float4), wq scaled
__global__ __launch_bounds__(256) void castw4(const float* __restrict__ wq,
                                              const float* __restrict__ wk,
                                              const float* __restrict__ wv,
                                              const float* __restrict__ wo,
                                              unsigned short* __restrict__ oq,
                                              unsigned short* __restrict__ ok,
                                              unsigned short* __restrict__ ov,
                                              unsigned short* __restrict__ oo,
                                              float qscale) {
  const int tensor = blockIdx.x >> 12;
  const int i = (blockIdx.x & 4095) * 256 + threadIdx.x;
  const float* in = tensor == 0 ? wq : tensor == 1 ? wk : tensor == 2 ? wv : wo;
  unsigned short* out = tensor == 0 ? oq : tensor == 1 ? ok : tensor == 2 ? ov : oo;
  const float s = tensor == 0 ? qscale : 1.0f;
  const float4 v = reinterpret_cast<const float4*>(in)[i];
  ushort4 o;
  o.x = f2u(v.x * s);
  o.y = f2u(v.y * s);
  o.z = f2u(v.z * s);
  o.w = f2u(v.w * s);
  reinterpret_cast<ushort4*>(out)[i] = o;
}

// ---------------- 256x256 8-phase GEMM (unchanged from R6/R7) ----------
template <int OUT>
__global__ __launch_bounds__(512, 2)
void gemm256(const unsigned short* __restrict__ A,
             const unsigned short* __restrict__ B,
             unsigned short* __restrict__ Cb,
             float* __restrict__ Cf,
             const float* __restrict__ bias,
             int M, int N, int K) {
  extern __shared__ unsigned short lds[];
  const int t = threadIdx.x;
  const int w = t >> 6;
  const int l = t & 63;
  const int wm = w >> 2;
  const int wn = w & 3;
  const int fr = l & 15;
  const int fkb = l >> 4;
  const int key = fr & 7;
  const int sslot = (l & 7) ^ (l >> 3);

  const int m0 = blockIdx.y * 256;
  const int n0 = blockIdx.x * 256;
  const int T = K >> 6;

  auto stage = [&](const unsigned short* G, int rb, int kt2, int h, int ldsbase) {
    const int d2 = kt2 & 1;
    const int rt = h * 128 + w * 16 + (l >> 3);
    const unsigned short* s0 = G + (size_t)(rb + rt) * K + kt2 * 64 + sslot * 8;
    unsigned short* dst = lds + ldsbase + d2 * 16384 + h * 8192 + w * 1024;
    gload_lds16(s0, dst);
    gload_lds16(s0 + (size_t)8 * K, dst + 512);
  };

  floatx4 acc[8][4];
#pragma unroll
  for (int m = 0; m < 8; m++)
#pragma unroll
    for (int n = 0; n < 4; n++) acc[m][n] = (floatx4){0.f, 0.f, 0.f, 0.f};

  stage(A, m0, 0, 0, 0);
  stage(A, m0, 0, 1, 0);
  stage(B, n0, 0, 0, 32768);
  stage(B, n0, 0, 1, 32768);
  if (1 < T) {
    stage(B, n0, 1, 0, 32768);
    stage(B, n0, 1, 1, 32768);
    asm volatile("s_waitcnt vmcnt(4)" ::: "memory");
  } else {
    asm volatile("s_waitcnt vmcnt(0)" ::: "memory");
  }
  __builtin_amdgcn_s_barrier();

#define GPHASE(q, STAGE_STMT)                                               \
  {                                                                         \
    bf16x8 a00 = *reinterpret_cast<const bf16x8*>(                          \
        Ab + (wm * 128 + (2 * (q)) * 16 + fr) * 64 + ((fkb ^ key)) * 8);    \
    bf16x8 a01 = *reinterpret_cast<const bf16x8*>(                          \
        Ab + (wm * 128 + (2 * (q)) * 16 + fr) * 64 + (((4 + fkb) ^ key)) * 8); \
    bf16x8 a10 = *reinterpret_cast<const bf16x8*>(                          \
        Ab + (wm * 128 + (2 * (q) + 1) * 16 + fr) * 64 + ((fkb ^ key)) * 8);\
    bf16x8 a11 = *reinterpret_cast<const bf16x8*>(                          \
        Ab + (wm * 128 + (2 * (q) + 1) * 16 + fr) * 64 + (((4 + fkb) ^ key)) * 8); \
    STAGE_STMT;                                                             \
    __builtin_amdgcn_s_barrier();                                           \
    asm volatile("s_waitcnt lgkmcnt(0)");                                   \
    __builtin_amdgcn_s_setprio(1);                                          \
    _Pragma("unroll")                                                       \
    for (int n = 0; n < 4; n++) {                                           \
      acc[2 * (q)][n] = mfma16(a00, bfr[0][n], acc[2 * (q)][n]);            \
      acc[2 * (q)][n] = mfma16(a01, bfr[1][n], acc[2 * (q)][n]);            \
      acc[2 * (q) + 1][n] = mfma16(a10, bfr[0][n], acc[2 * (q) + 1][n]);    \
      acc[2 * (q) + 1][n] = mfma16(a11, bfr[1][n], acc[2 * (q) + 1][n]);    \
    }                                                                       \
    __builtin_amdgcn_s_setprio(0);                                          \
    __builtin_amdgcn_s_barrier();                                           \
  }

  for (int kt = 0; kt < T; ++kt) {
    const int d = kt & 1;
    const unsigned short* Ab = lds + d * 16384;
    const unsigned short* Bb = lds + 32768 + d * 16384;

    bf16x8 bfr[2][4];
#pragma unroll
    for (int kk = 0; kk < 2; kk++)
#pragma unroll
      for (int n = 0; n < 4; n++)
        bfr[kk][n] = *reinterpret_cast<const bf16x8*>(
            Bb + (wn * 64 + n * 16 + fr) * 64 + (((kk * 4 + fkb) ^ key)) * 8);

    GPHASE(0, if (kt + 1 < T) stage(A, m0, kt + 1, 0, 0));
    GPHASE(1, if (kt + 1 < T) stage(A, m0, kt + 1, 1, 0));
    GPHASE(2, if (kt + 2 < T) stage(B, n0, kt + 2, 0, 32768));
    GPHASE(3, {
      if (kt + 2 < T) {
        stage(B, n0, kt + 2, 1, 32768);
        asm volatile("s_waitcnt vmcnt(4)" ::: "memory");
      } else {
        asm volatile("s_waitcnt vmcnt(0)" ::: "memory");
      }
    });
  }
#undef GPHASE

  const int er = (l >> 4) * 4;
  const int ec = l & 15;
#pragma unroll
  for (int m = 0; m < 8; m++) {
#pragma unroll
    for (int n = 0; n < 4; n++) {
      const int col = n0 + wn * 64 + n * 16 + ec;
      if (OUT == 2) {
        const int hv = col >> 7, dh = col & 127;
        const int row0 = m0 + wm * 128 + m * 16 + er;
        const int bb = row0 >> 11;
        const int t0 = row0 & 2047;
        unsigned short* vp =
            Cb + (((size_t)(bb * 16 + hv)) * 128 + dh) * 2048 + t0;
#pragma unroll
        for (int r = 0; r < 4; r++) vp[r] = f2u(acc[m][n][r]);
      } else {
#pragma unroll
        for (int r = 0; r < 4; r++) {
          const int row = m0 + wm * 128 + m * 16 + er + r;
          if (OUT == 1) {
            Cf[(size_t)row * N + col] = acc[m][n][r] + bias[col];
          } else {
            Cb[(size_t)row * N + col] = f2u(acc[m][n][r]);
          }
        }
      }
    }
  }
}

// ---------------- flash attention (R7 shell + exp2 shuffle-free softmax) ----
// Y2: (8192 x 4096) bf16, cols [0,2048)=Q (pre-scaled by log2e/sqrt(Dh)),
// [2048,4096)=K.  Vtg: [64 bh][128 dh][2048 t] bf16.
// Block: 4 waves x 32 q-rows = 128 q-rows. KV tile = 64. K/V single-buffered
// (50KB static LDS). Scores in log2 domain -> exp2f. Softmax common path is
// shuffle-free (per-lane partial max + one __any vote); lsum per-lane
// partials reduced once in epilogue. No setprio (m190).
__global__ __launch_bounds__(256, 2)
void attn_kernel(const unsigned short* __restrict__ Y2,
                 const unsigned short* __restrict__ Vtg,
                 unsigned short* __restrict__ att) {
  __shared__ unsigned short Kt[64 * 128];   // 16 KB, [kvrow][slot16 swz]
  __shared__ unsigned short Vt[128 * 64];   // 16 KB, [dh][slot8 swz]
  __shared__ unsigned short Pl[4][32 * 72]; // 18 KB, per-wave P, stride 72

  const int t = threadIdx.x;
  const int w = t >> 6;
  const int l = t & 63;
  const int bid = blockIdx.x;
  const int bh = bid & 63;
  const int qt = bid >> 6;  // 0..15, 128 q-rows each
  const int b = bh >> 4;
  const int h = bh & 15;

  const size_t ybase = (size_t)b * 2048 * 4096 + (size_t)h * 128;
  const unsigned short* Qp = Y2 + ybase;
  const unsigned short* Kp = Y2 + ybase + 2048;
  const unsigned short* Vp = Vtg + (size_t)bh * 128 * 2048;

  const int fr = l & 15;
  const int fkb = l >> 4;
  const int key = fr & 7;

  const int ksr = t >> 4;
  const int ksl = (t & 15) ^ (ksr & 7);
  const unsigned short* Ksrc = Kp + (size_t)ksr * 4096 + ksl * 8;

  const int vsr = t >> 3;
  const int vsl = (t & 7) ^ (vsr & 7);
  const unsigned short* Vsrc = Vp + (size_t)vsr * 2048 + vsl * 8;

  bf16x8 qf[2][4];
#pragma unroll
  for (int i = 0; i < 2; i++)
#pragma unroll
    for (int kk = 0; kk < 4; kk++)
      qf[i][kk] = *reinterpret_cast<const bf16x8*>(
          &Qp[(size_t)(qt * 128 + w * 32 + i * 16 + fr) * 4096 + kk * 32 + fkb * 8]);

  floatx4 oacc[2][8];
#pragma unroll
  for (int i = 0; i < 2; i++)
#pragma unroll
    for (int nt = 0; nt < 8; nt++) oacc[i][nt] = (floatx4){0.f, 0.f, 0.f, 0.f};
  float mrun[2][4], lsum[2][4];
#pragma unroll
  for (int i = 0; i < 2; i++)
#pragma unroll
    for (int r = 0; r < 4; r++) {
      mrun[i][r] = -INFINITY;
      lsum[i][r] = 0.f;
    }

  unsigned short* Pw = &Pl[w][0];

  // prologue: stage K(0), V(0)
#pragma unroll
  for (int c = 0; c < 4; c++)
    gload_lds16(Ksrc + (size_t)c * 16 * 4096, &Kt[c * 2048 + w * 512]);
#pragma unroll
  for (int c = 0; c < 4; c++)
    gload_lds16(Vsrc + (size_t)c * 32 * 2048, &Vt[c * 2048 + w * 512]);
  __syncthreads();  // vmcnt drained: K(0), V(0) ready

  for (int kv = 0; kv < 2048; kv += 64) {
    // ---- QK^T: 32 q-rows x 64 kv from Kt (log2-domain scores) ----
    floatx4 sacc[2][4];
#pragma unroll
    for (int i = 0; i < 2; i++)
#pragma unroll
      for (int nt = 0; nt < 4; nt++) sacc[i][nt] = (floatx4){0.f, 0.f, 0.f, 0.f};
#pragma unroll
    for (int nt = 0; nt < 4; nt++) {
#pragma unroll
      for (int kk = 0; kk < 4; kk++) {
        bf16x8 kf = *reinterpret_cast<const bf16x8*>(
            &Kt[((nt * 16 + fr) * 16 + ((kk * 4 + fkb) ^ key)) * 8]);
        sacc[0][nt] = mfma16(qf[0][kk], kf, sacc[0][nt]);
        sacc[1][nt] = mfma16(qf[1][kk], kf, sacc[1][nt]);
      }
    }

    // ---- softmax: shuffle-free common path (defer-max THR=11.5 log2) ----
    float mx4[2][4];
    float dmax = -INFINITY;
#pragma unroll
    for (int i = 0; i < 2; i++)
#pragma unroll
      for (int r = 0; r < 4; r++) {
        mx4[i][r] = fmaxf(fmaxf(sacc[i][0][r], sacc[i][1][r]),
                          fmaxf(sacc[i][2][r], sacc[i][3][r]));
        dmax = fmaxf(dmax, mx4[i][r] - mrun[i][r]);
      }
    if (__any(dmax > 11.5f)) {  // rare: full reduce + rescale (uniform per 16-grp)
#pragma unroll
      for (int i = 0; i < 2; i++)
#pragma unroll
        for (int r = 0; r < 4; r++) {
          float mx = mx4[i][r];
          mx = fmaxf(mx, __shfl_xor(mx, 1));
          mx = fmaxf(mx, __shfl_xor(mx, 2));
          mx = fmaxf(mx, __shfl_xor(mx, 4));
          mx = fmaxf(mx, __shfl_xor(mx, 8));
          const float mn = fmaxf(mrun[i][r], mx);
          const float alpha = exp2f(mrun[i][r] - mn);
          mrun[i][r] = mn;
          lsum[i][r] *= alpha;
#pragma unroll
          for (int nt = 0; nt < 8; nt++) oacc[i][nt][r] *= alpha;
        }
    }
#pragma unroll
    for (int i = 0; i < 2; i++)
#pragma unroll
      for (int r = 0; r < 4; r++) {
        const float m = mrun[i][r];
        const float p0 = exp2f(sacc[i][0][r] - m);
        const float p1 = exp2f(sacc[i][1][r] - m);
        const float p2 = exp2f(sacc[i][2][r] - m);
        const float p3 = exp2f(sacc[i][3][r] - m);
        lsum[i][r] += (p0 + p1) + (p2 + p3);
        const int pr = i * 16 + fkb * 4 + r;
        Pw[pr * 72 + fr] = f2u(p0);
        Pw[pr * 72 + 16 + fr] = f2u(p1);
        Pw[pr * 72 + 32 + fr] = f2u(p2);
        Pw[pr * 72 + 48 + fr] = f2u(p3);
      }

    __syncthreads();  // bar1: all Kt reads done; prior V-stage drained

    // ---- stage K(kv+64); latency hides under PV ----
    if (kv + 64 < 2048) {
#pragma unroll
      for (int c = 0; c < 4; c++)
        gload_lds16(Ksrc + (size_t)(kv + 64 + c * 16) * 4096,
                    &Kt[c * 2048 + w * 512]);
    }

    // ---- PV: out(32x128) += P(32x64) @ V(64x128) ----
    bf16x8 pf[2][2];
#pragma unroll
    for (int i = 0; i < 2; i++) {
      pf[i][0] = *reinterpret_cast<const bf16x8*>(&Pw[(i * 16 + fr) * 72 + fkb * 8]);
      pf[i][1] = *reinterpret_cast<const bf16x8*>(&Pw[(i * 16 + fr) * 72 + 32 + fkb * 8]);
    }
#pragma unroll
    for (int nt = 0; nt < 8; nt++) {
      const unsigned short* vr = &Vt[(nt * 16 + fr) * 64];
      bf16x8 vf0 = *reinterpret_cast<const bf16x8*>(vr + (fkb ^ key) * 8);
      bf16x8 vf1 = *reinterpret_cast<const bf16x8*>(vr + ((fkb + 4) ^ key) * 8);
#pragma unroll
      for (int i = 0; i < 2; i++) {
        oacc[i][nt] = mfma16(pf[i][0], vf0, oacc[i][nt]);
        oacc[i][nt] = mfma16(pf[i][1], vf1, oacc[i][nt]);
      }
    }

    __syncthreads();  // bar2: all Vt reads done; K(kv+64) drained

    // ---- stage V(kv+64); latency hides under next QK^T+softmax ----
    if (kv + 64 < 2048) {
#pragma unroll
      for (int c = 0; c < 4; c++)
        gload_lds16(Vsrc + (size_t)c * 32 * 2048 + (kv + 64),
                    &Vt[c * 2048 + w * 512]);
    }
  }

  // ---- epilogue: reduce per-lane lsum partials once, then write ----
#pragma unroll
  for (int i = 0; i < 2; i++) {
#pragma unroll
    for (int r = 0; r < 4; r++) {
      float s = lsum[i][r];
      s += __shfl_xor(s, 1);
      s += __shfl_xor(s, 2);
      s += __shfl_xor(s, 4);
      s += __shfl_xor(s, 8);
      const float inv = 1.0f / s;
      const int row = qt * 128 + w * 32 + i * 16 + fkb * 4 + r;
      unsigned short* op = att + ((size_t)b * 2048 + row) * 2048 + h * 128 + fr;
#pragma unroll
      for (int nt = 0; nt < 8; nt++) op[nt * 16] = f2u(oacc[i][nt][r] * inv);
    }
  }
}

// ---------------- launch ----------------
extern "C" void kernel_launch(void* const* d_in, const int* in_sizes, int n_in,
                              void* d_out, int out_size, void* d_ws, size_t ws_size,
                              hipStream_t stream) {
  const float* x = (const float*)d_in[0];
  const float* wq = (const float*)d_in[1];
  const float* wk = (const float*)d_in[2];
  const float* wv = (const float*)d_in[3];
  const float* wo = (const float*)d_in[4];
  const float* bo = (const float*)d_in[5];

  unsigned short* ws = (unsigned short*)d_ws;
  unsigned short* x16 = ws;                      // 16,777,216
  unsigned short* wqkv16 = x16 + 16777216;       // 12,582,912
  unsigned short* wo16 = wqkv16 + 12582912;      // 4,194,304
  unsigned short* Y2 = wo16 + 4194304;           // 33,554,432 (8192 x 4096, Q|K)
  unsigned short* Vtg = Y2 + 33554432;           // 16,777,216 (64 x 128 x 2048)
  unsigned short* att16 = Vtg + 16777216;        // 16,777,216
  // total 100,663,296 ushorts = 201.3 MB

  // log2(e)/sqrt(128): scores land in log2 domain -> exp2f softmax
  const float sscale = 0.12751744900765256f;

  hipFuncSetAttribute(reinterpret_cast<const void*>(gemm256<0>),
                      hipFuncAttributeMaxDynamicSharedMemorySize, 131072);
  hipFuncSetAttribute(reinterpret_cast<const void*>(gemm256<1>),
                      hipFuncAttributeMaxDynamicSharedMemorySize, 131072);
  hipFuncSetAttribute(reinterpret_cast<const void*>(gemm256<2>),
                      hipFuncAttributeMaxDynamicSharedMemorySize, 131072);

  castk<<<16384, 256, 0, stream>>>(x, x16, 4194304, 1.0f);
  castw4<<<16384, 256, 0, stream>>>(wq, wk, wv, wo,
                                    wqkv16, wqkv16 + 4194304,
                                    wqkv16 + 8388608, wo16, sscale);

  // Q,K projections -> Y2 (row-major)
  dim3 gqk(16, 32);
  gemm256<0><<<gqk, 512, 131072, stream>>>(x16, wqkv16, Y2, nullptr, nullptr,
                                           8192, 4096, 2048);
  // V projection -> Vtg (transposed per head)
  dim3 gv(8, 32);
  gemm256<2><<<gv, 512, 131072, stream>>>(x16, wqkv16 + 8388608, Vtg, nullptr,
                                          nullptr, 8192, 2048, 2048);

  attn_kernel<<<1024, 256, 0, stream>>>(Y2, Vtg, att16);

  dim3 go(8, 32);
  gemm256<1><<<go, 512, 131072, stream>>>(att16, wo16, nullptr, (float*)d_out,
                                          bo, 8192, 2048, 2048);
}